// Round 8
// baseline (298.608 us; speedup 1.0000x reference)
//
#include <hip/hip_runtime.h>
#include <math.h>

#define EMBED 512
#define NHEAD 8
#define HD 64
#define NUM_CLS 4
#define WIN 32
#define WLEN 65          // 2*WIN+1
#define PATCH_LEN 8192
#define S_TOT 8196       // NUM_CLS + PATCH_LEN
#define QKV_LD 1536
#define VT_LD 8200       // padded, multiple of 8 -> 16B-aligned rows

#define CCH 128
#define NCHUNK ((S_TOT + CCH - 1) / CCH)   // 65
#define PSTRIDE 68

typedef short bf16x8 __attribute__((ext_vector_type(8)));
typedef float f32x4 __attribute__((ext_vector_type(4)));

__device__ __forceinline__ unsigned short f2bf(float f) {
    unsigned u = __float_as_uint(f);
    return (unsigned short)((u + 0x7fffu + ((u >> 16) & 1u)) >> 16);
}
__device__ __forceinline__ float bf2f(unsigned short v) {
    return __uint_as_float((unsigned)v << 16);
}
__device__ __forceinline__ void gll16(const unsigned short* g, unsigned short* l) {
    __builtin_amdgcn_global_load_lds((const __attribute__((address_space(1))) void*)g,
                                     (__attribute__((address_space(3))) void*)l, 16, 0, 0);
}
__device__ __forceinline__ bf16x8 pack8(float4 lo, float4 hi) {
    bf16x8 r;
    r[0] = (short)f2bf(lo.x); r[1] = (short)f2bf(lo.y);
    r[2] = (short)f2bf(lo.z); r[3] = (short)f2bf(lo.w);
    r[4] = (short)f2bf(hi.x); r[5] = (short)f2bf(hi.y);
    r[6] = (short)f2bf(hi.z); r[7] = (short)f2bf(hi.w);
    return r;
}

// ---------------- weights cast + rope cos/sin table precompute ----------------
__global__ __launch_bounds__(256) void cast_w(const float* __restrict__ wq,
                                              const float* __restrict__ wo,
                                              const float* __restrict__ coords,
                                              unsigned short* __restrict__ wqb,
                                              unsigned short* __restrict__ wob,
                                              ushort2* __restrict__ rt)
{
    if (blockIdx.x < 1024) {
        const int n2 = 3 * EMBED * EMBED;
        const int n3 = EMBED * EMBED;
        const int i = (blockIdx.x * 256 + threadIdx.x) * 4;
        const float* src;
        unsigned short* dst;
        int j;
        if (i < n2)           { src = wq; dst = wqb; j = i; }
        else if (i < n2 + n3) { src = wo; dst = wob; j = i - n2; }
        else return;
        const float4 v = *(const float4*)(src + j);
        ushort4 o;
        o.x = f2bf(v.x); o.y = f2bf(v.y); o.z = f2bf(v.z); o.w = f2bf(v.w);
        *(ushort4*)(dst + j) = o;
    } else {
        const int idx = (blockIdx.x - 1024) * 256 + threadIdx.x;   // 0..262143
        const int l = idx >> 5, pr = idx & 31;
        const float cxy = coords[l * 2 + (pr >> 4)] * 1e-5f;
        const float f = cxy * __expf(-(float)(pr & 15) * 0.5756462732485114f);
        float sn, cs;
        __sincosf(f, &sn, &cs);
        ushort2 e; e.x = f2bf(cs); e.y = f2bf(sn);
        rt[idx] = e;
    }
}

// ---------------- QKV GEMM: qkv = x(fp32) @ w_qkv^T + b, rope + vT fused ----------------
// ROUND-4 VERIFIED VERSION (best in-bench total 168.5): triple-buffer main loop,
// counted vmcnt(6), XOR swizzle, single-phase full-tile EX epilogues.
#define EXW 136   // EX row stride (ushorts); 272B, 16B-aligned
__global__ __launch_bounds__(256, 3) void gemm_qkv(const float* __restrict__ X,
                                                   const unsigned short* __restrict__ B,
                                                   const float* __restrict__ bias,
                                                   unsigned short* __restrict__ C,
                                                   const ushort2* __restrict__ RT,
                                                   unsigned short* __restrict__ vT)
{
    const int M = S_TOT, N = 3 * EMBED, K = EMBED;
    __shared__ __align__(16) unsigned short SMEM[24576];   // A x3 | B x3; EX overlay
    unsigned short* EX = SMEM;

    const int tid = threadIdx.x;
    const int lane = tid & 63, w = tid >> 6;
    const int xcd = blockIdx.x & 7;
    const int s = blockIdx.x >> 3;          // 0..107
    const int bm = xcd + 8 * (s / 12);
    const int bn = s % 12;
    if (bm >= 65) return;

    const int ar0 = tid >> 2;
    const int colsw = ((tid & 3) ^ ((tid >> 3) & 3)) * 8;
    int gm0 = bm * 128 + ar0;       if (gm0 >= M) gm0 = M - 1;
    int gm1 = bm * 128 + ar0 + 64;  if (gm1 >= M) gm1 = M - 1;
    const float* Xp0 = X + (size_t)gm0 * K + colsw;
    const float* Xp1 = X + (size_t)gm1 * K + colsw;
    const unsigned short* pb0 = B + (size_t)(bn * 128 + ar0) * K + colsw;
    const unsigned short* pb1 = B + (size_t)(bn * 128 + ar0 + 64) * K + colsw;

    const int wr = (w & 1) * 64;
    const int wc = (w >> 1) * 64;
    const int fr = lane & 15;
    const int fkswz = ((lane >> 4) ^ ((fr >> 1) & 3)) * 8;

    f32x4 acc[4][4];
#pragma unroll
    for (int mi = 0; mi < 4; ++mi)
#pragma unroll
        for (int ni = 0; ni < 4; ++ni) acc[mi][ni] = (f32x4)0.f;

    unsigned short* A0 = SMEM;
    unsigned short* A1 = SMEM + 4096;
    unsigned short* A2 = SMEM + 8192;
    unsigned short* Bb0 = SMEM + 12288;
    unsigned short* Bb1 = SMEM + 16384;
    unsigned short* Bb2 = SMEM + 20480;

    float4 n00, n01, n10, n11;
    {
        const float4 a00 = *(const float4*)(Xp0);
        const float4 a01 = *(const float4*)(Xp0 + 4);
        const float4 a10 = *(const float4*)(Xp1);
        const float4 a11 = *(const float4*)(Xp1 + 4);
        gll16(pb0, Bb0 + tid * 8);
        gll16(pb1, Bb0 + (tid + 256) * 8);
        *(bf16x8*)(A0 + tid * 8) = pack8(a00, a01);
        *(bf16x8*)(A0 + (tid + 256) * 8) = pack8(a10, a11);
        asm volatile("" ::: "memory");
        n00 = *(const float4*)(Xp0 + 32);
        n01 = *(const float4*)(Xp0 + 36);
        n10 = *(const float4*)(Xp1 + 32);
        n11 = *(const float4*)(Xp1 + 36);
        gll16(pb0 + 32, Bb1 + tid * 8);
        gll16(pb1 + 32, Bb1 + (tid + 256) * 8);
    }

    for (int it = 0; it < 16; ++it) {
        if (it < 15) asm volatile("s_waitcnt vmcnt(6) lgkmcnt(0)" ::: "memory");
        else         asm volatile("s_waitcnt vmcnt(0) lgkmcnt(0)" ::: "memory");
        __builtin_amdgcn_s_barrier();

        float4 m00, m01, m10, m11;
        const bool pf = (it < 14);
        if (pf) {
            const int kf = (it + 2) * 32;
            m00 = *(const float4*)(Xp0 + kf);
            m01 = *(const float4*)(Xp0 + kf + 4);
            m10 = *(const float4*)(Xp1 + kf);
            m11 = *(const float4*)(Xp1 + kf + 4);
            gll16(pb0 + kf, Bb2 + tid * 8);
            gll16(pb1 + kf, Bb2 + (tid + 256) * 8);
        }

        bf16x8 af[4], bfr[4];
#pragma unroll
        for (int mi = 0; mi < 4; ++mi)
            af[mi] = *(const bf16x8*)(A0 + (wr + mi * 16 + fr) * 32 + fkswz);
#pragma unroll
        for (int ni = 0; ni < 4; ++ni)
            bfr[ni] = *(const bf16x8*)(Bb0 + (wc + ni * 16 + fr) * 32 + fkswz);
#pragma unroll
        for (int mi = 0; mi < 4; ++mi)
#pragma unroll
            for (int ni = 0; ni < 4; ++ni)
                acc[mi][ni] = __builtin_amdgcn_mfma_f32_16x16x32_bf16(af[mi], bfr[ni], acc[mi][ni], 0, 0, 0);

        if (it < 15) {
            *(bf16x8*)(A1 + tid * 8) = pack8(n00, n01);
            *(bf16x8*)(A1 + (tid + 256) * 8) = pack8(n10, n11);
        }
        if (pf) { n00 = m00; n01 = m01; n10 = m10; n11 = m11; }

        unsigned short* t;
        t = A0;  A0 = A1;  A1 = A2;  A2 = t;
        t = Bb0; Bb0 = Bb1; Bb1 = Bb2; Bb2 = t;
    }
    __syncthreads();   // staging dead; EX overlay safe

    const int ccol = bn * 128 + wc + fr;

    if (bn < 8) {
        // ---- q/k: rope from RT, single-phase full-tile EX staging + coalesced store ----
        const ushort2* rt = (const ushort2*)EX;
#pragma unroll
        for (int i0 = 0; i0 < 4; ++i0) {
            const int i = tid + 256 * i0;
            const int rloc = i >> 3, ch = i & 7;
            int l = bm * 128 + rloc - NUM_CLS;
            l = l < 0 ? 0 : (l > PATCH_LEN - 1 ? PATCH_LEN - 1 : l);
            gll16((const unsigned short*)(RT + (size_t)l * 32 + ch * 4), EX + i * 8);
        }
        __syncthreads();

        unsigned pv[4][4][2];
#pragma unroll
        for (int mi = 0; mi < 4; ++mi) {
#pragma unroll
            for (int r = 0; r < 4; ++r) {
                const int rloc = wr + mi * 16 + (lane >> 4) * 4 + r;
                const int row = bm * 128 + rloc;
                const bool patch = (row >= NUM_CLS) && (row < M);
#pragma unroll
                for (int ni = 0; ni < 4; ++ni) {
                    const int col = ccol + ni * 16;
                    const float biased = acc[mi][ni][r] + bias[col];
                    const float prt = __shfl_xor(biased, 1);
                    float outv = biased;
                    if (patch) {
                        const ushort2 e = rt[rloc * 32 + ((col & 63) >> 1)];
                        const float cs = bf2f(e.x), sn = bf2f(e.y);
                        outv = (col & 1) ? (biased * cs + prt * sn)
                                         : (biased * cs - prt * sn);
                    }
                    const unsigned us = f2bf(outv);
                    if (r & 1) pv[mi][ni][r >> 1] |= us << 16;
                    else       pv[mi][ni][r >> 1] = us;
                }
            }
        }
        __syncthreads();   // rt reads drained; EX reuse safe
#pragma unroll
        for (int mi = 0; mi < 4; ++mi) {
#pragma unroll
            for (int r = 0; r < 4; ++r) {
                const int rl = wr + mi * 16 + (lane >> 4) * 4 + r;
#pragma unroll
                for (int ni = 0; ni < 4; ++ni) {
                    const unsigned pw = pv[mi][ni][r >> 1];
                    EX[rl * EXW + wc + fr + ni * 16] =
                        (unsigned short)((r & 1) ? (pw >> 16) : (pw & 0xffff));
                }
            }
        }
        __syncthreads();
#pragma unroll
        for (int i = 0; i < 8; ++i) {
            const int idx = tid + 256 * i;    // 0..2047
            const int rowl = idx >> 4, ch = idx & 15;
            const int grow = bm * 128 + rowl;
            if (grow < M)
                *(bf16x8*)(C + (size_t)grow * N + bn * 128 + ch * 8) =
                    *(const bf16x8*)(EX + rowl * EXW + ch * 8);
        }
    } else {
        const int dbase = (bn - 8) * 128;
        // ---- v: C via EX staging ----
#pragma unroll
        for (int mi = 0; mi < 4; ++mi) {
#pragma unroll
            for (int r = 0; r < 4; ++r) {
                const int rl = wr + mi * 16 + (lane >> 4) * 4 + r;
#pragma unroll
                for (int ni = 0; ni < 4; ++ni)
                    EX[rl * EXW + wc + fr + ni * 16] = f2bf(acc[mi][ni][r] + bias[ccol + ni * 16]);
            }
        }
        __syncthreads();
#pragma unroll
        for (int i = 0; i < 8; ++i) {
            const int idx = tid + 256 * i;
            const int rowl = idx >> 4, ch = idx & 15;
            const int grow = bm * 128 + rowl;
            if (grow < M)
                *(bf16x8*)(C + (size_t)grow * N + bn * 128 + ch * 8) =
                    *(const bf16x8*)(EX + rowl * EXW + ch * 8);
        }
        __syncthreads();
        // ---- vT: single-phase full 128(dim)x128(tok) transpose staging ----
#pragma unroll
        for (int mi = 0; mi < 4; ++mi) {
            const int tok0 = wr + mi * 16 + (lane >> 4) * 4;
            const int rw = bm * 128 + tok0;
#pragma unroll
            for (int ni = 0; ni < 4; ++ni) {
                const int col = ccol + ni * 16;
                const int dloc = wc + fr + 16 * ni;    // 0..127 across the 4 waves
                ushort4 o;
                o.x = (rw + 0 < M) ? f2bf(acc[mi][ni][0] + bias[col]) : (unsigned short)0;
                o.y = (rw + 1 < M) ? f2bf(acc[mi][ni][1] + bias[col]) : (unsigned short)0;
                o.z = (rw + 2 < M) ? f2bf(acc[mi][ni][2] + bias[col]) : (unsigned short)0;
                o.w = (rw + 3 < M) ? f2bf(acc[mi][ni][3] + bias[col]) : (unsigned short)0;
                *(ushort4*)(EX + dloc * EXW + tok0) = o;
            }
        }
        __syncthreads();
#pragma unroll
        for (int i = 0; i < 2; ++i) {
            const int idx = tid + 256 * i;    // 0..511
            const int d = idx >> 2;           // 0..127
            const int tch = (idx & 3) * 32;
            const int gtok = bm * 128 + tch;
            unsigned short* dst = vT + (size_t)(dbase + d) * VT_LD + gtok;
            const unsigned short* srcl = EX + d * EXW + tch;
            if (gtok + 32 <= VT_LD) {
#pragma unroll
                for (int c2 = 0; c2 < 32; c2 += 8)
                    *(bf16x8*)(dst + c2) = *(const bf16x8*)(srcl + c2);
            } else {
                for (int c2 = 0; c2 < 32; ++c2)
                    if (gtok + c2 < VT_LD) dst[c2] = srcl[c2];
            }
        }
    }
}

// ---------------- out GEMM: out = attn @ w_out^T + b (fp32), cls-combine fused ----------
// R4 main loop + epilogue. NEW: cls_attn_combine is folded in -- the four bm==0
// blocks compute the combined cls rows (bit-identical math) into LDS COMB and
// patch the affected A-fragment lanes each iteration; attnb rows 0..3 are never
// read from global (they stay unwritten workspace). One launch + drain saved.
__global__ __launch_bounds__(256) void gemm_out(const unsigned short* __restrict__ A,
                                                const unsigned short* __restrict__ B,
                                                const float* __restrict__ bias,
                                                float* __restrict__ C,
                                                const float* __restrict__ part)
{
    const int M = S_TOT, N = EMBED, K = EMBED;
    // staging [0,18432) ushorts; COMB [18432,20480) = 4x512 bf16; fp32 EXF overlay
    __shared__ __align__(16) unsigned short SMEM[20480];
    unsigned short* COMB = SMEM + 18432;
    const int tid = threadIdx.x;
    const int lane = tid & 63, w = tid >> 6;
    const int bn = blockIdx.x, bm = blockIdx.y;

    if (bm == 0) {
        // combine: row qi (0..3), col c = j*64 + c0  (h=j, d=c0)
        const int qi = tid >> 6;
        const int c0 = tid & 63;
#pragma unroll
        for (int j = 0; j < 8; ++j) {
            const float* pbase = part + ((size_t)(j * NCHUNK) * 4 + qi) * PSTRIDE;
            float Mx = -INFINITY;
            for (int c = 0; c < NCHUNK; ++c)
                Mx = fmaxf(Mx, pbase[(size_t)c * 4 * PSTRIDE + 64]);
            float acc = 0.f, L = 0.f;
            for (int c = 0; c < NCHUNK; ++c) {
                const float* pb = pbase + (size_t)c * 4 * PSTRIDE;
                const float sc = expf(pb[64] - Mx);
                acc += sc * pb[c0];
                L   += sc * pb[65];
            }
            COMB[qi * 512 + j * 64 + c0] = f2bf(acc / L);
        }
        __syncthreads();   // COMB visible to all waves before the K-loop
    }

    const int ar0 = tid >> 2;
    const int colsw = ((tid & 3) ^ ((tid >> 3) & 3)) * 8;
    int gm0 = bm * 64 + ar0;  if (gm0 >= M) gm0 = M - 1;
    const unsigned short* pa0 = A + (size_t)gm0 * K + colsw;
    const unsigned short* pb0 = B + (size_t)(bn * 128 + ar0) * K + colsw;
    const unsigned short* pb1 = B + (size_t)(bn * 128 + ar0 + 64) * K + colsw;

    const int wr = (w & 1) * 32;
    const int wc = (w >> 1) * 64;
    const int fr = lane & 15;
    const int fkswz = (((lane >> 4) ^ ((fr >> 1) & 3))) * 8;
    // lanes holding A rows 0..3: bm==0, wr==0, mi==0, fr<4
    const bool patchlane = (bm == 0) && (wr == 0) && (fr < 4);

    f32x4 acc[2][4];
#pragma unroll
    for (int mi = 0; mi < 2; ++mi)
#pragma unroll
        for (int ni = 0; ni < 4; ++ni) acc[mi][ni] = (f32x4)0.f;

    unsigned short *As0 = SMEM,         *As1 = SMEM + 2048,  *As2 = SMEM + 4096;
    unsigned short *Bs0 = SMEM + 6144,  *Bs1 = SMEM + 10240, *Bs2 = SMEM + 14336;

    gll16(pa0, As0 + tid * 8);
    gll16(pb0, Bs0 + tid * 8);
    gll16(pb1, Bs0 + (tid + 256) * 8);
    asm volatile("" ::: "memory");
    gll16(pa0 + 32, As1 + tid * 8);
    gll16(pb0 + 32, Bs1 + tid * 8);
    gll16(pb1 + 32, Bs1 + (tid + 256) * 8);

    for (int it = 0; it < 16; ++it) {
        if (it < 15) asm volatile("s_waitcnt vmcnt(3)" ::: "memory");
        else         asm volatile("s_waitcnt vmcnt(0)" ::: "memory");
        __builtin_amdgcn_s_barrier();
        if (it < 14) {
            const int k0 = (it + 2) * 32;
            gll16(pa0 + k0, As2 + tid * 8);
            gll16(pb0 + k0, Bs2 + tid * 8);
            gll16(pb1 + k0, Bs2 + (tid + 256) * 8);
        }
        bf16x8 af[2], bfr[4];
#pragma unroll
        for (int mi = 0; mi < 2; ++mi)
            af[mi] = *(const bf16x8*)(As0 + (wr + mi * 16 + fr) * 32 + fkswz);
        {   // patch rows 0..3 (logical k chunk of af is (lane>>4), linear in COMB)
            const bf16x8 ov = *(const bf16x8*)(COMB + (fr & 3) * 512 + it * 32 + (lane >> 4) * 8);
            af[0] = patchlane ? ov : af[0];
        }
#pragma unroll
        for (int ni = 0; ni < 4; ++ni)
            bfr[ni] = *(const bf16x8*)(Bs0 + (wc + ni * 16 + fr) * 32 + fkswz);
#pragma unroll
        for (int mi = 0; mi < 2; ++mi)
#pragma unroll
            for (int ni = 0; ni < 4; ++ni)
                acc[mi][ni] = __builtin_amdgcn_mfma_f32_16x16x32_bf16(af[mi], bfr[ni], acc[mi][ni], 0, 0, 0);
        unsigned short* t;
        t = As0; As0 = As1; As1 = As2; As2 = t;
        t = Bs0; Bs0 = Bs1; Bs1 = Bs2; Bs2 = t;
    }
    __syncthreads();   // all LDS reads drained; fp32 EXF overlay safe

    const int ccol = bn * 128 + wc + fr;
    float* EXF = (float*)SMEM;            // 64 x 132 fp32 = 33,792 B <= 36,864
#pragma unroll
    for (int mi = 0; mi < 2; ++mi) {
#pragma unroll
        for (int r = 0; r < 4; ++r) {
            const int rl = wr + mi * 16 + (lane >> 4) * 4 + r;
#pragma unroll
            for (int ni = 0; ni < 4; ++ni)
                EXF[rl * 132 + wc + fr + ni * 16] = acc[mi][ni][r] + bias[ccol + ni * 16];
        }
    }
    __syncthreads();
#pragma unroll
    for (int i = 0; i < 8; ++i) {
        const int idx = tid + 256 * i;    // 0..2047
        const int rowl = idx >> 5;        // 0..63
        const int ch = idx & 31;          // float4 chunk
        const int grow = bm * 64 + rowl;
        if (grow < M)
            *(float4*)(C + (size_t)grow * N + bn * 128 + ch * 4) =
                *(const float4*)(EXF + rowl * 132 + ch * 4);
    }
}

// ---------------- fused attention: 2048 patch blocks + 520 cls blocks ----------------
#define SW 116   // patch S stride (fp32)
#define PW 136   // patch P stride (bf16)

__global__ __launch_bounds__(256) void attn_fused(
    const unsigned short* __restrict__ qkv,   // [8196][1536] bf16, rope applied
    const unsigned short* __restrict__ vT,    // [512][VT_LD] v^T bf16
    float* __restrict__ part,
    unsigned short* __restrict__ attnb)       // [8196][512] bf16
{
    __shared__ __align__(16) char SM[33280];
    const int tid = threadIdx.x;
    const int lane = tid & 63, w = tid >> 6;

    if (blockIdx.x < 2048) {
        // ================= patch path =================
        const int l0 = (blockIdx.x >> 3) * 32;
        const int h = blockIdx.x & 7;
        unsigned short* Qs = (unsigned short*)SM;             // [0, 4096)
        unsigned short* Ks = (unsigned short*)(SM + 4096);    // [4096, 18432)
        unsigned short* Vt = (unsigned short*)SM;             // overlay after QK^T: [0, 16384)
        float* Sm = (float*)(SM + 18432);                     // [18432, 33280)

        {
            const int i = tid;
            const int t = i >> 3;
            const int dcl = (i & 7) ^ (t & 7);
            gll16(qkv + (size_t)(NUM_CLS + l0 + t) * QKV_LD + h * HD + dcl * 8, Qs + i * 8);
        }
        for (int i = tid; i < 896; i += 256) {
            const int c = i >> 3;
            const int dcl = (i & 7) ^ (c & 7);
            int tok = (c >= 104 && c < 108) ? (c - 104) : (l0 - 32 + c);
            tok = tok < 0 ? 0 : (tok > S_TOT - 1 ? S_TOT - 1 : tok);
            gll16(qkv + (size_t)tok * QKV_LD + EMBED + h * HD + dcl * 8, Ks + i * 8);
        }
        __syncthreads();

        bf16x8 qf[2][2];
#pragma unroll
        for (int mt = 0; mt < 2; ++mt)
#pragma unroll
            for (int ks = 0; ks < 2; ++ks) {
                const int row = mt * 16 + (lane & 15);
                const int dc = (ks * 4 + (lane >> 4)) ^ (row & 7);
                qf[mt][ks] = *(const bf16x8*)(Qs + row * 64 + dc * 8);
            }
        for (int idx = w; idx < 14; idx += 4) {
            const int mt = idx & 1, nt = idx >> 1;
            f32x4 acc = (f32x4)0.f;
#pragma unroll
            for (int ks = 0; ks < 2; ++ks) {
                const int kr = nt * 16 + (lane & 15);
                const int dc = (ks * 4 + (lane >> 4)) ^ (kr & 7);
                const bf16x8 kf = *(const bf16x8*)(Ks + kr * 64 + dc * 8);
                acc = __builtin_amdgcn_mfma_f32_16x16x32_bf16(qf[mt][ks], kf, acc, 0, 0, 0);
            }
            const int col = nt * 16 + (lane & 15);
            const int r0 = mt * 16 + (lane >> 4) * 4;
#pragma unroll
            for (int r = 0; r < 4; ++r) Sm[(r0 + r) * SW + col] = acc[r];
        }
        __syncthreads();   // all Q/K LDS reads drained -> Vt overlay safe

        // deferred V staging: latency hides under softmax; drained by the next sync
        for (int i = tid; i < 1024; i += 256) {
            const int d = i >> 4;
            const int kcl = (i & 15) ^ (d & 15);
            const int c0 = kcl * 8;
            int tokb = (c0 == 104) ? 0 : (l0 - 32 + c0);
            tokb = tokb < 0 ? 0 : (tokb > 8192 ? 8192 : tokb);
            gll16(vT + (size_t)(h * HD + d) * VT_LD + tokb, Vt + i * 8);
        }

        {
            const int t = tid >> 3, lq = tid & 7;
            float e[14];
            float m = -INFINITY;
#pragma unroll
            for (int j = 0; j < 14; ++j) {
                const int c = lq + 8 * j;
                bool valid;
                if (c >= 104) valid = (c < 108);
                else {
                    const int r = c - 4;
                    const int pos = l0 - 32 + r;
                    valid = (c >= 4) && (c < 100) && (r >= t) && (r <= t + 64) &&
                            (pos >= 0) && (pos < PATCH_LEN);
                }
                e[j] = valid ? Sm[t * SW + c] * 0.125f : -INFINITY;
                m = fmaxf(m, e[j]);
            }
#pragma unroll
            for (int off = 1; off < 8; off <<= 1) m = fmaxf(m, __shfl_xor(m, off, 64));
            float sum = 0.f;
#pragma unroll
            for (int j = 0; j < 14; ++j) { e[j] = expf(e[j] - m); sum += e[j]; }
#pragma unroll
            for (int off = 1; off < 8; off <<= 1) sum += __shfl_xor(sum, off, 64);
            const float inv = 1.f / sum;
            __syncthreads();
            unsigned short* P = (unsigned short*)Sm;
#pragma unroll
            for (int j = 0; j < 14; ++j) P[t * PW + lq + 8 * j] = f2bf(e[j] * inv);
            ushort2 z; z.x = 0; z.y = 0;
            *(ushort2*)(P + (tid >> 3) * PW + 112 + (tid & 7) * 2) = z;
        }
        __syncthreads();   // P ready; V staging landed

        {
            const unsigned short* P = (const unsigned short*)Sm;
            const int mt = w & 1;
            bf16x8 pf[4];
#pragma unroll
            for (int ks = 0; ks < 4; ++ks) {
                const int row = mt * 16 + (lane & 15);
                pf[ks] = *(const bf16x8*)(P + row * PW + ks * 32 + (lane >> 4) * 8);
            }
#pragma unroll
            for (int nn = 0; nn < 2; ++nn) {
                const int nt = (w >> 1) + nn * 2;
                f32x4 acc = (f32x4)0.f;
#pragma unroll
                for (int ks = 0; ks < 4; ++ks) {
                    const int d = nt * 16 + (lane & 15);
                    const int kc = (ks * 4 + (lane >> 4)) ^ (d & 15);
                    const bf16x8 vf = *(const bf16x8*)(Vt + d * 128 + kc * 8);
                    acc = __builtin_amdgcn_mfma_f32_16x16x32_bf16(pf[ks], vf, acc, 0, 0, 0);
                }
                const int dcol = nt * 16 + (lane & 15);
                const int r0 = mt * 16 + (lane >> 4) * 4;
#pragma unroll
                for (int r = 0; r < 4; ++r)
                    attnb[(size_t)(NUM_CLS + l0 + r0 + r) * EMBED + h * HD + dcol] = f2bf(acc[r]);
            }
        }
    } else {
        // ================= cls split-K path =================
        const int cid = blockIdx.x - 2048;
        const int h = cid & 7;
        const int c = cid >> 3;
        const int base = c * CCH;
        float* qs = (float*)SM;                               // [4][64]  1,024 B
        unsigned short* Kl = (unsigned short*)(SM + 1024);    // 16,384 B
        float* sc = (float*)(SM + 17408);                     // [4][128] 2,048 B
        float* ored = (float*)(SM + 19456);                   // [4][4][64] 4,096 B
        float* ml = (float*)(SM + 23552);                     // [4][2] 32 B

        {
            const int qi = tid >> 6, d = tid & 63;
            qs[qi * 64 + d] = bf2f(qkv[(size_t)qi * QKV_LD + h * HD + d]);
        }
        for (int i = tid; i < 1024; i += 256) {
            const int kr = i >> 3;
            const int dc = (i & 7) ^ (kr & 7);
            int j = base + kr; if (j > S_TOT - 1) j = S_TOT - 1;
            gll16(qkv + (size_t)j * QKV_LD + EMBED + h * HD + dc * 8, Kl + i * 8);
        }
        __syncthreads();

        {
            const int jj = tid & 127;
            const int qp = (tid >> 7) * 2;
            const int j = base + jj;
            float s0 = -INFINITY, s1 = -INFINITY;
            if (j < S_TOT) {
                float a0 = 0.f, a1 = 0.f;
#pragma unroll
                for (int cch = 0; cch < 8; ++cch) {
                    const int slot = cch ^ (jj & 7);
                    const bf16x8 kv8 = *(const bf16x8*)(Kl + jj * 64 + slot * 8);
#pragma unroll
                    for (int u = 0; u < 8; ++u) {
                        const float kf = bf2f((unsigned short)kv8[u]);
                        a0 += qs[(qp + 0) * 64 + cch * 8 + u] * kf;
                        a1 += qs[(qp + 1) * 64 + cch * 8 + u] * kf;
                    }
                }
                s0 = a0 * 0.125f; s1 = a1 * 0.125f;
            }
            sc[(qp + 0) * CCH + jj] = s0;
            sc[(qp + 1) * CCH + jj] = s1;
        }
        __syncthreads();

        {
            float m = fmaxf(sc[w * CCH + lane], sc[w * CCH + lane + 64]);
#pragma unroll
            for (int off = 32; off > 0; off >>= 1) m = fmaxf(m, __shfl_xor(m, off, 64));
            const float e0 = expf(sc[w * CCH + lane] - m);
            const float e1 = expf(sc[w * CCH + lane + 64] - m);
            sc[w * CCH + lane] = e0; sc[w * CCH + lane + 64] = e1;
            float lsum = e0 + e1;
#pragma unroll
            for (int off = 32; off > 0; off >>= 1) lsum += __shfl_xor(lsum, off, 64);
            if (lane == 0) { ml[w * 2 + 0] = m; ml[w * 2 + 1] = lsum; }
        }
        __syncthreads();

        {
            const int g = w, d = lane;
            float a0 = 0.f, a1 = 0.f, a2 = 0.f, a3 = 0.f;
            for (int jj = g; jj < CCH; jj += 4) {
                const int j = base + jj;
                if (j >= S_TOT) break;
                const float vv = bf2f(qkv[(size_t)j * QKV_LD + 2 * EMBED + h * HD + d]);
                a0 += sc[0 * CCH + jj] * vv; a1 += sc[1 * CCH + jj] * vv;
                a2 += sc[2 * CCH + jj] * vv; a3 += sc[3 * CCH + jj] * vv;
            }
            ored[(g * 4 + 0) * 64 + d] = a0; ored[(g * 4 + 1) * 64 + d] = a1;
            ored[(g * 4 + 2) * 64 + d] = a2; ored[(g * 4 + 3) * 64 + d] = a3;
        }
        __syncthreads();

        {
            const int qi = tid >> 6, d = tid & 63;
            const float o = ored[(0 * 4 + qi) * 64 + d] + ored[(1 * 4 + qi) * 64 + d] +
                            ored[(2 * 4 + qi) * 64 + d] + ored[(3 * 4 + qi) * 64 + d];
            float* pb = part + ((size_t)(h * NCHUNK + c) * 4 + qi) * PSTRIDE;
            pb[d] = o;
            if (d == 0) { pb[64] = ml[qi * 2 + 0]; pb[65] = ml[qi * 2 + 1]; }
        }
    }
}

extern "C" void kernel_launch(void* const* d_in, const int* in_sizes, int n_in,
                              void* d_out, int out_size, void* d_ws, size_t ws_size,
                              hipStream_t stream)
{
    const float* x      = (const float*)d_in[0];
    const float* coords = (const float*)d_in[1];
    const float* w_qkv  = (const float*)d_in[2];
    const float* b_qkv  = (const float*)d_in[3];
    const float* w_out  = (const float*)d_in[4];
    const float* b_out  = (const float*)d_in[5];
    float* out = (float*)d_out;

    // ---- ws layout: fully disjoint regions (~46.6 MB) ----
    char* p = (char*)d_ws;
    unsigned short* qkv   = (unsigned short*)p;  p += (size_t)S_TOT * QKV_LD * 2;
    unsigned short* vT    = (unsigned short*)p;  p += (size_t)EMBED * VT_LD * 2;
    unsigned short* attnb = (unsigned short*)p;  p += (size_t)S_TOT * EMBED * 2;
    float*          part  = (float*)p;           p += (size_t)NHEAD * NCHUNK * 4 * PSTRIDE * 4;
    unsigned short* wob   = (unsigned short*)p;  p += (size_t)EMBED * EMBED * 2;
    unsigned short* wqb   = (unsigned short*)p;  p += (size_t)3 * EMBED * EMBED * 2;
    ushort2*        ropet = (ushort2*)p;         // [PATCH_LEN*32] = 1 MB

    // d_out is written ONLY by the final GEMM. Output = pure function of d_in.

    // 1) weight casts + rope table (x cast is fused into gemm_qkv)
    cast_w<<<2048, 256, 0, stream>>>(w_qkv, w_out, coords, wqb, wob, ropet);

    // 2) qkv(bf16, rope fused, vT fused) = x(fp32) @ w_qkv^T + b_qkv
    gemm_qkv<<<864, 256, 0, stream>>>(x, wqb, b_qkv, qkv, ropet, vT);

    // 3) fused attention: 2048 patch-MFMA blocks + 520 cls split-K blocks
    attn_fused<<<2048 + NHEAD * NCHUNK, 256, 0, stream>>>(qkv, vT, part, attnb);

    // 4) out = attn @ w_out^T + b_out (fp32); cls combine fused into bm==0 blocks
    gemm_out<<<dim3(4, 129), 256, 0, stream>>>(attnb, wob, b_out, out, part);
}

// Round 9
// 162.366 us; speedup vs baseline: 1.8391x; 1.8391x over previous
//
#include <hip/hip_runtime.h>
#include <math.h>

#define EMBED 512
#define NHEAD 8
#define HD 64
#define NUM_CLS 4
#define WIN 32
#define WLEN 65          // 2*WIN+1
#define PATCH_LEN 8192
#define S_TOT 8196       // NUM_CLS + PATCH_LEN
#define QKV_LD 1536
#define VT_LD 8200       // padded, multiple of 8 -> 16B-aligned rows

#define CCH 128
#define NCHUNK ((S_TOT + CCH - 1) / CCH)   // 65
#define PSTRIDE 68

typedef short bf16x8 __attribute__((ext_vector_type(8)));
typedef float f32x4 __attribute__((ext_vector_type(4)));

__device__ __forceinline__ unsigned short f2bf(float f) {
    unsigned u = __float_as_uint(f);
    return (unsigned short)((u + 0x7fffu + ((u >> 16) & 1u)) >> 16);
}
__device__ __forceinline__ float bf2f(unsigned short v) {
    return __uint_as_float((unsigned)v << 16);
}
__device__ __forceinline__ void gll16(const unsigned short* g, unsigned short* l) {
    __builtin_amdgcn_global_load_lds((const __attribute__((address_space(1))) void*)g,
                                     (__attribute__((address_space(3))) void*)l, 16, 0, 0);
}
__device__ __forceinline__ bf16x8 pack8(float4 lo, float4 hi) {
    bf16x8 r;
    r[0] = (short)f2bf(lo.x); r[1] = (short)f2bf(lo.y);
    r[2] = (short)f2bf(lo.z); r[3] = (short)f2bf(lo.w);
    r[4] = (short)f2bf(hi.x); r[5] = (short)f2bf(hi.y);
    r[6] = (short)f2bf(hi.z); r[7] = (short)f2bf(hi.w);
    return r;
}

// ---------------- weights cast + rope cos/sin table precompute ----------------
__global__ __launch_bounds__(256) void cast_w(const float* __restrict__ wq,
                                              const float* __restrict__ wo,
                                              const float* __restrict__ coords,
                                              unsigned short* __restrict__ wqb,
                                              unsigned short* __restrict__ wob,
                                              ushort2* __restrict__ rt)
{
    if (blockIdx.x < 1024) {
        const int n2 = 3 * EMBED * EMBED;
        const int n3 = EMBED * EMBED;
        const int i = (blockIdx.x * 256 + threadIdx.x) * 4;
        const float* src;
        unsigned short* dst;
        int j;
        if (i < n2)           { src = wq; dst = wqb; j = i; }
        else if (i < n2 + n3) { src = wo; dst = wob; j = i - n2; }
        else return;
        const float4 v = *(const float4*)(src + j);
        ushort4 o;
        o.x = f2bf(v.x); o.y = f2bf(v.y); o.z = f2bf(v.z); o.w = f2bf(v.w);
        *(ushort4*)(dst + j) = o;
    } else {
        const int idx = (blockIdx.x - 1024) * 256 + threadIdx.x;   // 0..262143
        const int l = idx >> 5, pr = idx & 31;
        const float cxy = coords[l * 2 + (pr >> 4)] * 1e-5f;
        const float f = cxy * __expf(-(float)(pr & 15) * 0.5756462732485114f);
        float sn, cs;
        __sincosf(f, &sn, &cs);
        ushort2 e; e.x = f2bf(cs); e.y = f2bf(sn);
        rt[idx] = e;
    }
}

// ---------------- QKV GEMM: qkv = x(fp32) @ w_qkv^T + b, rope + vT fused ----------------
// ROUND-4 VERIFIED VERSION (best in-bench total 168.5): triple-buffer main loop,
// counted vmcnt(6), XOR swizzle, single-phase full-tile EX epilogues.
#define EXW 136   // EX row stride (ushorts); 272B, 16B-aligned
__global__ __launch_bounds__(256, 3) void gemm_qkv(const float* __restrict__ X,
                                                   const unsigned short* __restrict__ B,
                                                   const float* __restrict__ bias,
                                                   unsigned short* __restrict__ C,
                                                   const ushort2* __restrict__ RT,
                                                   unsigned short* __restrict__ vT)
{
    const int M = S_TOT, N = 3 * EMBED, K = EMBED;
    __shared__ __align__(16) unsigned short SMEM[24576];   // A x3 | B x3; EX overlay
    unsigned short* EX = SMEM;

    const int tid = threadIdx.x;
    const int lane = tid & 63, w = tid >> 6;
    const int xcd = blockIdx.x & 7;
    const int s = blockIdx.x >> 3;          // 0..107
    const int bm = xcd + 8 * (s / 12);
    const int bn = s % 12;
    if (bm >= 65) return;

    const int ar0 = tid >> 2;
    const int colsw = ((tid & 3) ^ ((tid >> 3) & 3)) * 8;
    int gm0 = bm * 128 + ar0;       if (gm0 >= M) gm0 = M - 1;
    int gm1 = bm * 128 + ar0 + 64;  if (gm1 >= M) gm1 = M - 1;
    const float* Xp0 = X + (size_t)gm0 * K + colsw;
    const float* Xp1 = X + (size_t)gm1 * K + colsw;
    const unsigned short* pb0 = B + (size_t)(bn * 128 + ar0) * K + colsw;
    const unsigned short* pb1 = B + (size_t)(bn * 128 + ar0 + 64) * K + colsw;

    const int wr = (w & 1) * 64;
    const int wc = (w >> 1) * 64;
    const int fr = lane & 15;
    const int fkswz = ((lane >> 4) ^ ((fr >> 1) & 3)) * 8;

    f32x4 acc[4][4];
#pragma unroll
    for (int mi = 0; mi < 4; ++mi)
#pragma unroll
        for (int ni = 0; ni < 4; ++ni) acc[mi][ni] = (f32x4)0.f;

    unsigned short* A0 = SMEM;
    unsigned short* A1 = SMEM + 4096;
    unsigned short* A2 = SMEM + 8192;
    unsigned short* Bb0 = SMEM + 12288;
    unsigned short* Bb1 = SMEM + 16384;
    unsigned short* Bb2 = SMEM + 20480;

    float4 n00, n01, n10, n11;
    {
        const float4 a00 = *(const float4*)(Xp0);
        const float4 a01 = *(const float4*)(Xp0 + 4);
        const float4 a10 = *(const float4*)(Xp1);
        const float4 a11 = *(const float4*)(Xp1 + 4);
        gll16(pb0, Bb0 + tid * 8);
        gll16(pb1, Bb0 + (tid + 256) * 8);
        *(bf16x8*)(A0 + tid * 8) = pack8(a00, a01);
        *(bf16x8*)(A0 + (tid + 256) * 8) = pack8(a10, a11);
        asm volatile("" ::: "memory");
        n00 = *(const float4*)(Xp0 + 32);
        n01 = *(const float4*)(Xp0 + 36);
        n10 = *(const float4*)(Xp1 + 32);
        n11 = *(const float4*)(Xp1 + 36);
        gll16(pb0 + 32, Bb1 + tid * 8);
        gll16(pb1 + 32, Bb1 + (tid + 256) * 8);
    }

    for (int it = 0; it < 16; ++it) {
        if (it < 15) asm volatile("s_waitcnt vmcnt(6) lgkmcnt(0)" ::: "memory");
        else         asm volatile("s_waitcnt vmcnt(0) lgkmcnt(0)" ::: "memory");
        __builtin_amdgcn_s_barrier();

        float4 m00, m01, m10, m11;
        const bool pf = (it < 14);
        if (pf) {
            const int kf = (it + 2) * 32;
            m00 = *(const float4*)(Xp0 + kf);
            m01 = *(const float4*)(Xp0 + kf + 4);
            m10 = *(const float4*)(Xp1 + kf);
            m11 = *(const float4*)(Xp1 + kf + 4);
            gll16(pb0 + kf, Bb2 + tid * 8);
            gll16(pb1 + kf, Bb2 + (tid + 256) * 8);
        }

        bf16x8 af[4], bfr[4];
#pragma unroll
        for (int mi = 0; mi < 4; ++mi)
            af[mi] = *(const bf16x8*)(A0 + (wr + mi * 16 + fr) * 32 + fkswz);
#pragma unroll
        for (int ni = 0; ni < 4; ++ni)
            bfr[ni] = *(const bf16x8*)(Bb0 + (wc + ni * 16 + fr) * 32 + fkswz);
#pragma unroll
        for (int mi = 0; mi < 4; ++mi)
#pragma unroll
            for (int ni = 0; ni < 4; ++ni)
                acc[mi][ni] = __builtin_amdgcn_mfma_f32_16x16x32_bf16(af[mi], bfr[ni], acc[mi][ni], 0, 0, 0);

        if (it < 15) {
            *(bf16x8*)(A1 + tid * 8) = pack8(n00, n01);
            *(bf16x8*)(A1 + (tid + 256) * 8) = pack8(n10, n11);
        }
        if (pf) { n00 = m00; n01 = m01; n10 = m10; n11 = m11; }

        unsigned short* t;
        t = A0;  A0 = A1;  A1 = A2;  A2 = t;
        t = Bb0; Bb0 = Bb1; Bb1 = Bb2; Bb2 = t;
    }
    __syncthreads();   // staging dead; EX overlay safe

    const int ccol = bn * 128 + wc + fr;

    if (bn < 8) {
        // ---- q/k: rope from RT, single-phase full-tile EX staging + coalesced store ----
        const ushort2* rt = (const ushort2*)EX;
#pragma unroll
        for (int i0 = 0; i0 < 4; ++i0) {
            const int i = tid + 256 * i0;
            const int rloc = i >> 3, ch = i & 7;
            int l = bm * 128 + rloc - NUM_CLS;
            l = l < 0 ? 0 : (l > PATCH_LEN - 1 ? PATCH_LEN - 1 : l);
            gll16((const unsigned short*)(RT + (size_t)l * 32 + ch * 4), EX + i * 8);
        }
        __syncthreads();

        unsigned pv[4][4][2];
#pragma unroll
        for (int mi = 0; mi < 4; ++mi) {
#pragma unroll
            for (int r = 0; r < 4; ++r) {
                const int rloc = wr + mi * 16 + (lane >> 4) * 4 + r;
                const int row = bm * 128 + rloc;
                const bool patch = (row >= NUM_CLS) && (row < M);
#pragma unroll
                for (int ni = 0; ni < 4; ++ni) {
                    const int col = ccol + ni * 16;
                    const float biased = acc[mi][ni][r] + bias[col];
                    const float prt = __shfl_xor(biased, 1);
                    float outv = biased;
                    if (patch) {
                        const ushort2 e = rt[rloc * 32 + ((col & 63) >> 1)];
                        const float cs = bf2f(e.x), sn = bf2f(e.y);
                        outv = (col & 1) ? (biased * cs + prt * sn)
                                         : (biased * cs - prt * sn);
                    }
                    const unsigned us = f2bf(outv);
                    if (r & 1) pv[mi][ni][r >> 1] |= us << 16;
                    else       pv[mi][ni][r >> 1] = us;
                }
            }
        }
        __syncthreads();   // rt reads drained; EX reuse safe
#pragma unroll
        for (int mi = 0; mi < 4; ++mi) {
#pragma unroll
            for (int r = 0; r < 4; ++r) {
                const int rl = wr + mi * 16 + (lane >> 4) * 4 + r;
#pragma unroll
                for (int ni = 0; ni < 4; ++ni) {
                    const unsigned pw = pv[mi][ni][r >> 1];
                    EX[rl * EXW + wc + fr + ni * 16] =
                        (unsigned short)((r & 1) ? (pw >> 16) : (pw & 0xffff));
                }
            }
        }
        __syncthreads();
#pragma unroll
        for (int i = 0; i < 8; ++i) {
            const int idx = tid + 256 * i;    // 0..2047
            const int rowl = idx >> 4, ch = idx & 15;
            const int grow = bm * 128 + rowl;
            if (grow < M)
                *(bf16x8*)(C + (size_t)grow * N + bn * 128 + ch * 8) =
                    *(const bf16x8*)(EX + rowl * EXW + ch * 8);
        }
    } else {
        const int dbase = (bn - 8) * 128;
        // ---- v: C via EX staging ----
#pragma unroll
        for (int mi = 0; mi < 4; ++mi) {
#pragma unroll
            for (int r = 0; r < 4; ++r) {
                const int rl = wr + mi * 16 + (lane >> 4) * 4 + r;
#pragma unroll
                for (int ni = 0; ni < 4; ++ni)
                    EX[rl * EXW + wc + fr + ni * 16] = f2bf(acc[mi][ni][r] + bias[ccol + ni * 16]);
            }
        }
        __syncthreads();
#pragma unroll
        for (int i = 0; i < 8; ++i) {
            const int idx = tid + 256 * i;
            const int rowl = idx >> 4, ch = idx & 15;
            const int grow = bm * 128 + rowl;
            if (grow < M)
                *(bf16x8*)(C + (size_t)grow * N + bn * 128 + ch * 8) =
                    *(const bf16x8*)(EX + rowl * EXW + ch * 8);
        }
        __syncthreads();
        // ---- vT: single-phase full 128(dim)x128(tok) transpose staging ----
#pragma unroll
        for (int mi = 0; mi < 4; ++mi) {
            const int tok0 = wr + mi * 16 + (lane >> 4) * 4;
            const int rw = bm * 128 + tok0;
#pragma unroll
            for (int ni = 0; ni < 4; ++ni) {
                const int col = ccol + ni * 16;
                const int dloc = wc + fr + 16 * ni;    // 0..127 across the 4 waves
                ushort4 o;
                o.x = (rw + 0 < M) ? f2bf(acc[mi][ni][0] + bias[col]) : (unsigned short)0;
                o.y = (rw + 1 < M) ? f2bf(acc[mi][ni][1] + bias[col]) : (unsigned short)0;
                o.z = (rw + 2 < M) ? f2bf(acc[mi][ni][2] + bias[col]) : (unsigned short)0;
                o.w = (rw + 3 < M) ? f2bf(acc[mi][ni][3] + bias[col]) : (unsigned short)0;
                *(ushort4*)(EX + dloc * EXW + tok0) = o;
            }
        }
        __syncthreads();
#pragma unroll
        for (int i = 0; i < 2; ++i) {
            const int idx = tid + 256 * i;    // 0..511
            const int d = idx >> 2;           // 0..127
            const int tch = (idx & 3) * 32;
            const int gtok = bm * 128 + tch;
            unsigned short* dst = vT + (size_t)(dbase + d) * VT_LD + gtok;
            const unsigned short* srcl = EX + d * EXW + tch;
            if (gtok + 32 <= VT_LD) {
#pragma unroll
                for (int c2 = 0; c2 < 32; c2 += 8)
                    *(bf16x8*)(dst + c2) = *(const bf16x8*)(srcl + c2);
            } else {
                for (int c2 = 0; c2 < 32; ++c2)
                    if (gtok + c2 < VT_LD) dst[c2] = srcl[c2];
            }
        }
    }
}

// ---------------- out GEMM: out = attn @ w_out^T + b (fp32) ----------------
// ROUND-4 VERIFIED VERSION: main loop triple-buffer/vmcnt(3); epilogue LDS-staged
// (36 KB flat SMEM overlay), coalesced float4 stores.
__global__ __launch_bounds__(256) void gemm_out(const unsigned short* __restrict__ A,
                                                const unsigned short* __restrict__ B,
                                                const float* __restrict__ bias,
                                                float* __restrict__ C)
{
    const int M = S_TOT, N = EMBED, K = EMBED;
    __shared__ __align__(16) unsigned short SMEM[18432];   // AS x3 | BS x3; fp32 EX overlay
    const int tid = threadIdx.x;
    const int lane = tid & 63, w = tid >> 6;
    const int bn = blockIdx.x, bm = blockIdx.y;

    const int ar0 = tid >> 2;
    const int colsw = ((tid & 3) ^ ((tid >> 3) & 3)) * 8;
    int gm0 = bm * 64 + ar0;  if (gm0 >= M) gm0 = M - 1;
    const unsigned short* pa0 = A + (size_t)gm0 * K + colsw;
    const unsigned short* pb0 = B + (size_t)(bn * 128 + ar0) * K + colsw;
    const unsigned short* pb1 = B + (size_t)(bn * 128 + ar0 + 64) * K + colsw;

    const int wr = (w & 1) * 32;
    const int wc = (w >> 1) * 64;
    const int fr = lane & 15;
    const int fkswz = (((lane >> 4) ^ ((fr >> 1) & 3))) * 8;

    f32x4 acc[2][4];
#pragma unroll
    for (int mi = 0; mi < 2; ++mi)
#pragma unroll
        for (int ni = 0; ni < 4; ++ni) acc[mi][ni] = (f32x4)0.f;

    unsigned short *As0 = SMEM,         *As1 = SMEM + 2048,  *As2 = SMEM + 4096;
    unsigned short *Bs0 = SMEM + 6144,  *Bs1 = SMEM + 10240, *Bs2 = SMEM + 14336;

    gll16(pa0, As0 + tid * 8);
    gll16(pb0, Bs0 + tid * 8);
    gll16(pb1, Bs0 + (tid + 256) * 8);
    asm volatile("" ::: "memory");
    gll16(pa0 + 32, As1 + tid * 8);
    gll16(pb0 + 32, Bs1 + tid * 8);
    gll16(pb1 + 32, Bs1 + (tid + 256) * 8);

    for (int it = 0; it < 16; ++it) {
        if (it < 15) asm volatile("s_waitcnt vmcnt(3)" ::: "memory");
        else         asm volatile("s_waitcnt vmcnt(0)" ::: "memory");
        __builtin_amdgcn_s_barrier();
        if (it < 14) {
            const int k0 = (it + 2) * 32;
            gll16(pa0 + k0, As2 + tid * 8);
            gll16(pb0 + k0, Bs2 + tid * 8);
            gll16(pb1 + k0, Bs2 + (tid + 256) * 8);
        }
        bf16x8 af[2], bfr[4];
#pragma unroll
        for (int mi = 0; mi < 2; ++mi)
            af[mi] = *(const bf16x8*)(As0 + (wr + mi * 16 + fr) * 32 + fkswz);
#pragma unroll
        for (int ni = 0; ni < 4; ++ni)
            bfr[ni] = *(const bf16x8*)(Bs0 + (wc + ni * 16 + fr) * 32 + fkswz);
#pragma unroll
        for (int mi = 0; mi < 2; ++mi)
#pragma unroll
            for (int ni = 0; ni < 4; ++ni)
                acc[mi][ni] = __builtin_amdgcn_mfma_f32_16x16x32_bf16(af[mi], bfr[ni], acc[mi][ni], 0, 0, 0);
        unsigned short* t;
        t = As0; As0 = As1; As1 = As2; As2 = t;
        t = Bs0; Bs0 = Bs1; Bs1 = Bs2; Bs2 = t;
    }
    __syncthreads();   // all LDS reads drained; fp32 EX overlay safe

    const int ccol = bn * 128 + wc + fr;
    float* EXF = (float*)SMEM;            // 64 x 132 fp32 = 33,792 B <= 36,864
#pragma unroll
    for (int mi = 0; mi < 2; ++mi) {
#pragma unroll
        for (int r = 0; r < 4; ++r) {
            const int rl = wr + mi * 16 + (lane >> 4) * 4 + r;
#pragma unroll
            for (int ni = 0; ni < 4; ++ni)
                EXF[rl * 132 + wc + fr + ni * 16] = acc[mi][ni][r] + bias[ccol + ni * 16];
        }
    }
    __syncthreads();
#pragma unroll
    for (int i = 0; i < 8; ++i) {
        const int idx = tid + 256 * i;    // 0..2047
        const int rowl = idx >> 5;        // 0..63
        const int ch = idx & 31;          // float4 chunk
        const int grow = bm * 64 + rowl;
        if (grow < M)
            *(float4*)(C + (size_t)grow * N + bn * 128 + ch * 4) =
                *(const float4*)(EXF + rowl * 132 + ch * 4);
    }
}

// ---------------- fused attention: 2048 patch blocks + 520 cls blocks ----------------
#define SW 116   // patch S stride (fp32)
#define PW 136   // patch P stride (bf16)

__global__ __launch_bounds__(256) void attn_fused(
    const unsigned short* __restrict__ qkv,   // [8196][1536] bf16, rope applied
    const unsigned short* __restrict__ vT,    // [512][VT_LD] v^T bf16
    float* __restrict__ part,
    unsigned short* __restrict__ attnb)       // [8196][512] bf16
{
    __shared__ __align__(16) char SM[33280];
    const int tid = threadIdx.x;
    const int lane = tid & 63, w = tid >> 6;

    if (blockIdx.x < 2048) {
        // ================= patch path =================
        const int l0 = (blockIdx.x >> 3) * 32;
        const int h = blockIdx.x & 7;
        unsigned short* Qs = (unsigned short*)SM;             // [0, 4096)
        unsigned short* Ks = (unsigned short*)(SM + 4096);    // [4096, 18432)
        unsigned short* Vt = (unsigned short*)SM;             // overlay after QK^T: [0, 16384)
        float* Sm = (float*)(SM + 18432);                     // [18432, 33280)

        {
            const int i = tid;
            const int t = i >> 3;
            const int dcl = (i & 7) ^ (t & 7);
            gll16(qkv + (size_t)(NUM_CLS + l0 + t) * QKV_LD + h * HD + dcl * 8, Qs + i * 8);
        }
        for (int i = tid; i < 896; i += 256) {
            const int c = i >> 3;
            const int dcl = (i & 7) ^ (c & 7);
            int tok = (c >= 104 && c < 108) ? (c - 104) : (l0 - 32 + c);
            tok = tok < 0 ? 0 : (tok > S_TOT - 1 ? S_TOT - 1 : tok);
            gll16(qkv + (size_t)tok * QKV_LD + EMBED + h * HD + dcl * 8, Ks + i * 8);
        }
        __syncthreads();

        bf16x8 qf[2][2];
#pragma unroll
        for (int mt = 0; mt < 2; ++mt)
#pragma unroll
            for (int ks = 0; ks < 2; ++ks) {
                const int row = mt * 16 + (lane & 15);
                const int dc = (ks * 4 + (lane >> 4)) ^ (row & 7);
                qf[mt][ks] = *(const bf16x8*)(Qs + row * 64 + dc * 8);
            }
        for (int idx = w; idx < 14; idx += 4) {
            const int mt = idx & 1, nt = idx >> 1;
            f32x4 acc = (f32x4)0.f;
#pragma unroll
            for (int ks = 0; ks < 2; ++ks) {
                const int kr = nt * 16 + (lane & 15);
                const int dc = (ks * 4 + (lane >> 4)) ^ (kr & 7);
                const bf16x8 kf = *(const bf16x8*)(Ks + kr * 64 + dc * 8);
                acc = __builtin_amdgcn_mfma_f32_16x16x32_bf16(qf[mt][ks], kf, acc, 0, 0, 0);
            }
            const int col = nt * 16 + (lane & 15);
            const int r0 = mt * 16 + (lane >> 4) * 4;
#pragma unroll
            for (int r = 0; r < 4; ++r) Sm[(r0 + r) * SW + col] = acc[r];
        }
        __syncthreads();   // all Q/K LDS reads drained -> Vt overlay safe

        // deferred V staging: latency hides under softmax; drained by the next sync
        for (int i = tid; i < 1024; i += 256) {
            const int d = i >> 4;
            const int kcl = (i & 15) ^ (d & 15);
            const int c0 = kcl * 8;
            int tokb = (c0 == 104) ? 0 : (l0 - 32 + c0);
            tokb = tokb < 0 ? 0 : (tokb > 8192 ? 8192 : tokb);
            gll16(vT + (size_t)(h * HD + d) * VT_LD + tokb, Vt + i * 8);
        }

        {
            const int t = tid >> 3, lq = tid & 7;
            float e[14];
            float m = -INFINITY;
#pragma unroll
            for (int j = 0; j < 14; ++j) {
                const int c = lq + 8 * j;
                bool valid;
                if (c >= 104) valid = (c < 108);
                else {
                    const int r = c - 4;
                    const int pos = l0 - 32 + r;
                    valid = (c >= 4) && (c < 100) && (r >= t) && (r <= t + 64) &&
                            (pos >= 0) && (pos < PATCH_LEN);
                }
                e[j] = valid ? Sm[t * SW + c] * 0.125f : -INFINITY;
                m = fmaxf(m, e[j]);
            }
#pragma unroll
            for (int off = 1; off < 8; off <<= 1) m = fmaxf(m, __shfl_xor(m, off, 64));
            float sum = 0.f;
#pragma unroll
            for (int j = 0; j < 14; ++j) { e[j] = expf(e[j] - m); sum += e[j]; }
#pragma unroll
            for (int off = 1; off < 8; off <<= 1) sum += __shfl_xor(sum, off, 64);
            const float inv = 1.f / sum;
            __syncthreads();
            unsigned short* P = (unsigned short*)Sm;
#pragma unroll
            for (int j = 0; j < 14; ++j) P[t * PW + lq + 8 * j] = f2bf(e[j] * inv);
            ushort2 z; z.x = 0; z.y = 0;
            *(ushort2*)(P + (tid >> 3) * PW + 112 + (tid & 7) * 2) = z;
        }
        __syncthreads();   // P ready; V staging landed

        {
            const unsigned short* P = (const unsigned short*)Sm;
            const int mt = w & 1;
            bf16x8 pf[4];
#pragma unroll
            for (int ks = 0; ks < 4; ++ks) {
                const int row = mt * 16 + (lane & 15);
                pf[ks] = *(const bf16x8*)(P + row * PW + ks * 32 + (lane >> 4) * 8);
            }
#pragma unroll
            for (int nn = 0; nn < 2; ++nn) {
                const int nt = (w >> 1) + nn * 2;
                f32x4 acc = (f32x4)0.f;
#pragma unroll
                for (int ks = 0; ks < 4; ++ks) {
                    const int d = nt * 16 + (lane & 15);
                    const int kc = (ks * 4 + (lane >> 4)) ^ (d & 15);
                    const bf16x8 vf = *(const bf16x8*)(Vt + d * 128 + kc * 8);
                    acc = __builtin_amdgcn_mfma_f32_16x16x32_bf16(pf[ks], vf, acc, 0, 0, 0);
                }
                const int dcol = nt * 16 + (lane & 15);
                const int r0 = mt * 16 + (lane >> 4) * 4;
#pragma unroll
                for (int r = 0; r < 4; ++r)
                    attnb[(size_t)(NUM_CLS + l0 + r0 + r) * EMBED + h * HD + dcol] = f2bf(acc[r]);
            }
        }
    } else {
        // ================= cls split-K path =================
        const int cid = blockIdx.x - 2048;
        const int h = cid & 7;
        const int c = cid >> 3;
        const int base = c * CCH;
        float* qs = (float*)SM;                               // [4][64]  1,024 B
        unsigned short* Kl = (unsigned short*)(SM + 1024);    // 16,384 B
        float* sc = (float*)(SM + 17408);                     // [4][128] 2,048 B
        float* ored = (float*)(SM + 19456);                   // [4][4][64] 4,096 B
        float* ml = (float*)(SM + 23552);                     // [4][2] 32 B

        {
            const int qi = tid >> 6, d = tid & 63;
            qs[qi * 64 + d] = bf2f(qkv[(size_t)qi * QKV_LD + h * HD + d]);
        }
        for (int i = tid; i < 1024; i += 256) {
            const int kr = i >> 3;
            const int dc = (i & 7) ^ (kr & 7);
            int j = base + kr; if (j > S_TOT - 1) j = S_TOT - 1;
            gll16(qkv + (size_t)j * QKV_LD + EMBED + h * HD + dc * 8, Kl + i * 8);
        }
        __syncthreads();

        {
            const int jj = tid & 127;
            const int qp = (tid >> 7) * 2;
            const int j = base + jj;
            float s0 = -INFINITY, s1 = -INFINITY;
            if (j < S_TOT) {
                float a0 = 0.f, a1 = 0.f;
#pragma unroll
                for (int cch = 0; cch < 8; ++cch) {
                    const int slot = cch ^ (jj & 7);
                    const bf16x8 kv8 = *(const bf16x8*)(Kl + jj * 64 + slot * 8);
#pragma unroll
                    for (int u = 0; u < 8; ++u) {
                        const float kf = bf2f((unsigned short)kv8[u]);
                        a0 += qs[(qp + 0) * 64 + cch * 8 + u] * kf;
                        a1 += qs[(qp + 1) * 64 + cch * 8 + u] * kf;
                    }
                }
                s0 = a0 * 0.125f; s1 = a1 * 0.125f;
            }
            sc[(qp + 0) * CCH + jj] = s0;
            sc[(qp + 1) * CCH + jj] = s1;
        }
        __syncthreads();

        {
            float m = fmaxf(sc[w * CCH + lane], sc[w * CCH + lane + 64]);
#pragma unroll
            for (int off = 32; off > 0; off >>= 1) m = fmaxf(m, __shfl_xor(m, off, 64));
            const float e0 = expf(sc[w * CCH + lane] - m);
            const float e1 = expf(sc[w * CCH + lane + 64] - m);
            sc[w * CCH + lane] = e0; sc[w * CCH + lane + 64] = e1;
            float lsum = e0 + e1;
#pragma unroll
            for (int off = 32; off > 0; off >>= 1) lsum += __shfl_xor(lsum, off, 64);
            if (lane == 0) { ml[w * 2 + 0] = m; ml[w * 2 + 1] = lsum; }
        }
        __syncthreads();

        {
            const int g = w, d = lane;
            float a0 = 0.f, a1 = 0.f, a2 = 0.f, a3 = 0.f;
            for (int jj = g; jj < CCH; jj += 4) {
                const int j = base + jj;
                if (j >= S_TOT) break;
                const float vv = bf2f(qkv[(size_t)j * QKV_LD + 2 * EMBED + h * HD + d]);
                a0 += sc[0 * CCH + jj] * vv; a1 += sc[1 * CCH + jj] * vv;
                a2 += sc[2 * CCH + jj] * vv; a3 += sc[3 * CCH + jj] * vv;
            }
            ored[(g * 4 + 0) * 64 + d] = a0; ored[(g * 4 + 1) * 64 + d] = a1;
            ored[(g * 4 + 2) * 64 + d] = a2; ored[(g * 4 + 3) * 64 + d] = a3;
        }
        __syncthreads();

        {
            const int qi = tid >> 6, d = tid & 63;
            const float o = ored[(0 * 4 + qi) * 64 + d] + ored[(1 * 4 + qi) * 64 + d] +
                            ored[(2 * 4 + qi) * 64 + d] + ored[(3 * 4 + qi) * 64 + d];
            float* pb = part + ((size_t)(h * NCHUNK + c) * 4 + qi) * PSTRIDE;
            pb[d] = o;
            if (d == 0) { pb[64] = ml[qi * 2 + 0]; pb[65] = ml[qi * 2 + 1]; }
        }
    }
}

// ---------------- cls combine: PARALLELIZED (32 blocks, 4-way chunk split) ----------
// Old version: 8 blocks, 130 serial chunk-loads/thread (~15-20 us, hidden from
// top-5). New: block per (h,qi); 4 chunk-groups x 64 d-lanes; 17 serial
// loads/thread; split-logsumexp merge via LDS (standard rescale, <=2 ulp delta).
__global__ __launch_bounds__(256) void cls_attn_combine(const float* __restrict__ part,
                                                        unsigned short* __restrict__ attn)
{
    const int h = blockIdx.x >> 2;       // 0..7
    const int qi = blockIdx.x & 3;       // 0..3
    const int g = threadIdx.x >> 6;      // 0..3 chunk group
    const int d = threadIdx.x & 63;
    __shared__ float sM[4];
    __shared__ float sL[4];
    __shared__ float sAcc[4][64];

    float m = -INFINITY;
    for (int c = g; c < NCHUNK; c += 4)
        m = fmaxf(m, part[((size_t)(h * NCHUNK + c) * 4 + qi) * PSTRIDE + 64]);
    float acc = 0.f, L = 0.f;
    for (int c = g; c < NCHUNK; c += 4) {
        const float* pb = part + ((size_t)(h * NCHUNK + c) * 4 + qi) * PSTRIDE;
        const float s = expf(pb[64] - m);
        acc += s * pb[d];
        L   += s * pb[65];
    }
    if (d == 0) sM[g] = m;
    __syncthreads();
    const float M = fmaxf(fmaxf(sM[0], sM[1]), fmaxf(sM[2], sM[3]));
    const float rs = expf(m - M);
    sAcc[g][d] = acc * rs;
    if (d == 0) sL[g] = L * rs;
    __syncthreads();
    if (g == 0) {
        const float a  = sAcc[0][d] + sAcc[1][d] + sAcc[2][d] + sAcc[3][d];
        const float Lt = sL[0] + sL[1] + sL[2] + sL[3];
        attn[(size_t)qi * EMBED + h * HD + d] = f2bf(a / Lt);
    }
}

extern "C" void kernel_launch(void* const* d_in, const int* in_sizes, int n_in,
                              void* d_out, int out_size, void* d_ws, size_t ws_size,
                              hipStream_t stream)
{
    const float* x      = (const float*)d_in[0];
    const float* coords = (const float*)d_in[1];
    const float* w_qkv  = (const float*)d_in[2];
    const float* b_qkv  = (const float*)d_in[3];
    const float* w_out  = (const float*)d_in[4];
    const float* b_out  = (const float*)d_in[5];
    float* out = (float*)d_out;

    // ---- ws layout: fully disjoint regions (~46.6 MB) ----
    char* p = (char*)d_ws;
    unsigned short* qkv   = (unsigned short*)p;  p += (size_t)S_TOT * QKV_LD * 2;
    unsigned short* vT    = (unsigned short*)p;  p += (size_t)EMBED * VT_LD * 2;
    unsigned short* attnb = (unsigned short*)p;  p += (size_t)S_TOT * EMBED * 2;
    float*          part  = (float*)p;           p += (size_t)NHEAD * NCHUNK * 4 * PSTRIDE * 4;
    unsigned short* wob   = (unsigned short*)p;  p += (size_t)EMBED * EMBED * 2;
    unsigned short* wqb   = (unsigned short*)p;  p += (size_t)3 * EMBED * EMBED * 2;
    ushort2*        ropet = (ushort2*)p;         // [PATCH_LEN*32] = 1 MB

    // d_out is written ONLY by the final GEMM. Output = pure function of d_in.

    // 1) weight casts + rope table (x cast is fused into gemm_qkv)
    cast_w<<<2048, 256, 0, stream>>>(w_qkv, w_out, coords, wqb, wob, ropet);

    // 2) qkv(bf16, rope fused, vT fused) = x(fp32) @ w_qkv^T + b_qkv
    gemm_qkv<<<864, 256, 0, stream>>>(x, wqb, b_qkv, qkv, ropet, vT);

    // 3) fused attention: 2048 patch-MFMA blocks + 520 cls split-K blocks
    attn_fused<<<2048 + NHEAD * NCHUNK, 256, 0, stream>>>(qkv, vT, part, attnb);

    // 4) cls combine (32 blocks, 4-way chunk-split logsumexp merge)
    cls_attn_combine<<<NHEAD * 4, 256, 0, stream>>>(part, attnb);

    // 5) out = attn @ w_out^T + b_out (fp32)
    gemm_out<<<dim3(4, 129), 256, 0, stream>>>(attnb, wob, b_out, out);
}